// Round 8
// baseline (110.326 us; speedup 1.0000x reference)
//
#include <hip/hip_runtime.h>

#define NFEAT 38

typedef __attribute__((ext_vector_type(8))) short bf16x8;
typedef __attribute__((ext_vector_type(4))) float f32x4;

// bf16 table row bases
#define R_SP   0      // 512 fused species rows
#define R_AB   512    // 128 fused ability rows
#define R_IT   640    // 256 fused item rows
#define R_T1   896    // 404: (f3,f4,f5)   = f3*4+f4*2+f5
#define R_T2   1300   // 128: (f6,f11,f12) = f6*4+f11*2+f12  (hp=f6/31 folded in)
#define R_T3   1428   // 24 : (f7,f8)      = f7*8+f8
#define R_T4   1452   // 32 : (f9,f10)     = f9*2+f10
#define R_T5   1484   // 64 : (f13,f14,f15)= f13*8+f14*2+f15
#define R_T6   1548   // 169: (f16,f17)    = f16*13+f17
#define R_T7   1717   // 169: (f18,f19)
#define R_T8   1886   // 169: (f20,f21)
#define R_T9   2055   // 13 : f22
#define R_ACT  2068   // 512: actions_emb (bf16)
#define R_BITS 2580   // 5632: 2580 + fi*512 + half*256 + byte
#define NROWS  8212   // total rows (x 512 B = 4,204,544 B)

// k_prep block layout (1024 threads each)
#define B_FUSED  0     // 224 blocks: fused sp/ab/it rows (4 rows, 4-way K-split)
#define B_WBT    224   // 64 blocks : fragment-ordered bf16 mlp_w (wfrag)
#define B_BITS   288   // 1408 blocks: bits byte tables (4 rows/block)
#define B_MERGED 1696  // 421 blocks: merged one-hot/boost/action rows (4 rows/block)
#define NB_PREP  2117

__device__ __forceinline__ unsigned short f2bf(float f) {
    unsigned int u = __float_as_uint(f);
    u += 0x7fffu + ((u >> 16) & 1u);   // round-to-nearest-even
    return (unsigned short)(u >> 16);
}

// ---------------------------------------------------------------------------
// K0: table prep (fused rows / wfrag / bits tables / merged rows)
// ---------------------------------------------------------------------------
__global__ __launch_bounds__(1024) void k_prep(
    const float* __restrict__ sp_tbl, const float* __restrict__ ab_tbl,
    const float* __restrict__ it_tbl, const float* __restrict__ sp_emb,
    const float* __restrict__ ab_emb, const float* __restrict__ it_emb,
    const float* __restrict__ act_emb, const float* __restrict__ agg_w,
    const float* __restrict__ agg_b,  const float* __restrict__ mlp_w,
    unsigned short* __restrict__ tbl, unsigned short* __restrict__ wfrag)
{
    __shared__ float rowbuf[4 * 512];
    __shared__ float part[4][4][256];
    int blk = blockIdx.x, t = threadIdx.x, c = t & 255;
#define W(x) agg_w[(size_t)(x) * 256 + c]

    if (blk < B_WBT) {
        // ---- fused species/ability/item rows: 4 rows/block, K split 4 ways ----
        int r0 = blk << 2;
        const float* src; const float* emb; int len, wbase; bool add_b;
        if (r0 < 512)      { src = sp_tbl + (size_t)r0 * 512;           emb = sp_emb + (size_t)r0 * 256;           len = 512; wbase = 0;   add_b = true;  }
        else if (r0 < 640) { int q = r0 - 512; src = ab_tbl + (size_t)q * 128; emb = ab_emb + (size_t)q * 256; len = 128; wbase = 512; add_b = false; }
        else               { int q = r0 - 640; src = it_tbl + (size_t)q * 256; emb = it_emb + (size_t)q * 256; len = 256; wbase = 640; add_b = false; }
        int tot = len << 2;
        for (int i = t; i < tot; i += 1024) rowbuf[i] = src[i];
        __syncthreads();
        int kq   = t >> 8;
        int len4 = len >> 2;
        int kbeg = kq * len4, kend = kbeg + len4;
        float a0 = 0.f, a1 = 0.f, a2 = 0.f, a3 = 0.f;
        #pragma unroll 4
        for (int k = kbeg; k < kend; ++k) {
            float w = W(wbase + k);
            a0 += rowbuf[k] * w;
            a1 += rowbuf[len + k] * w;
            a2 += rowbuf[2 * len + k] * w;
            a3 += rowbuf[3 * len + k] * w;
        }
        part[0][kq][c] = a0; part[1][kq][c] = a1;
        part[2][kq][c] = a2; part[3][kq][c] = a3;
        __syncthreads();
        int row = t >> 8;
        float s = part[row][0][c] + part[row][1][c] + part[row][2][c] + part[row][3][c]
                + emb[row * 256 + c] + (add_b ? agg_b[c] : 0.f);
        tbl[(size_t)(r0 + row) * 256 + c] = f2bf(s);
        return;
    }
    if (blk < B_BITS) {
        // ---- fragment-ordered bf16 mlp_w:
        //      wfrag[(((nt*8 + k0g)*64 + lane)*8 + j] = mlp_w[k0g*32 + (lane>>4)*8 + j][nt*16 + (lane&15)]
        int idx = ((blk - B_WBT) << 10) + t;   // 0..65535
        int j   = idx & 7;
        int fl  = (idx >> 3) & 63;
        int k0g = (idx >> 9) & 7;
        int nt  = idx >> 12;
        int k   = k0g * 32 + (fl >> 4) * 8 + j;
        int col = nt * 16 + (fl & 15);
        wfrag[idx] = f2bf(mlp_w[(size_t)k * 256 + col]);
        return;
    }
    if (blk < B_MERGED) {
        // ---- bits byte tables: 4 rows per block ----
        int idx = ((blk - B_BITS) << 10) + t;
        int row = idx >> 8;                 // 0..5631 = tseg*256 + byte
        int tseg = row >> 8, byte = row & 255;
        int base = 1171 + 16 * (tseg >> 1) + 8 * (tseg & 1);
        float acc = 0.f;
        #pragma unroll
        for (int j = 0; j < 8; ++j)
            if ((byte >> j) & 1) acc += W(base + j);
        tbl[(size_t)(R_BITS + row) * 256 + c] = f2bf(acc);
        return;
    }
    {
        // ---- merged category rows: 4 rows per block ----
        int r = ((blk - B_MERGED) << 2) + (t >> 8);   // 0..1683
        int row; float acc;
        if (r < 404)       { int f3 = r >> 2, f4 = (r >> 1) & 1, f5 = r & 1;
                             acc = W(896 + f3) + W(997 + f4) + W(999 + f5); row = R_T1 + r; }
        else if (r < 532)  { int i = r - 404; int f6 = i >> 2, f11 = (i >> 1) & 1, f12 = i & 1;
                             acc = W(1001 + f6) + (float)f6 * (1.f / 31.f) * W(1347)
                                 + W(1062 + f11) + W(1064 + f12); row = R_T2 + i; }
        else if (r < 556)  { int i = r - 532; acc = W(1033 + (i >> 3)) + W(1036 + (i & 7)); row = R_T3 + i; }
        else if (r < 588)  { int i = r - 556; acc = W(1044 + (i >> 1)) + W(1060 + (i & 1)); row = R_T4 + i; }
        else if (r < 652)  { int i = r - 588; acc = W(1066 + (i >> 3)) + W(1074 + ((i >> 1) & 3)) + W(1078 + (i & 1)); row = R_T5 + i; }
        else if (r < 821)  { int i = r - 652; acc = W(1080 + i / 13) + W(1093 + i % 13); row = R_T6 + i; }
        else if (r < 990)  { int i = r - 821; acc = W(1106 + i / 13) + W(1119 + i % 13); row = R_T7 + i; }
        else if (r < 1159) { int i = r - 990; acc = W(1132 + i / 13) + W(1145 + i % 13); row = R_T8 + i; }
        else if (r < 1172) { int i = r - 1159; acc = W(1158 + i); row = R_T9 + i; }
        else               { int i = r - 1172; acc = act_emb[(size_t)i * 256 + c]; row = R_ACT + i; }
        tbl[(size_t)row * 256 + c] = f2bf(acc);
    }
#undef W
}

// ---------------------------------------------------------------------------
// K1: per-entity packed row indices (10 aligned dwordx4 over a 160 B window).
// ---------------------------------------------------------------------------
__global__ __launch_bounds__(256) void k_idx(
    const int* __restrict__ ent, unsigned short* __restrict__ ridx)
{
    int e = blockIdx.x * 256 + threadIdx.x;
    size_t bb = (size_t)e * (NFEAT * 4);
    const uint4* wp = reinterpret_cast<const uint4*>(
        reinterpret_cast<const char*>(ent) + (bb & ~(size_t)15));
    uint4 q0 = wp[0], q1 = wp[1], q2 = wp[2], q3 = wp[3], q4 = wp[4];
    uint4 q5 = wp[5], q6 = wp[6], q7 = wp[7], q8 = wp[8], q9 = wp[9];
    unsigned int v[40] = {q0.x,q0.y,q0.z,q0.w, q1.x,q1.y,q1.z,q1.w,
                          q2.x,q2.y,q2.z,q2.w, q3.x,q3.y,q3.z,q3.w,
                          q4.x,q4.y,q4.z,q4.w, q5.x,q5.y,q5.z,q5.w,
                          q6.x,q6.y,q6.z,q6.w, q7.x,q7.y,q7.z,q7.w,
                          q8.x,q8.y,q8.z,q8.w, q9.x,q9.y,q9.z,q9.w};
    int f[NFEAT];
    if (e & 1) {
        #pragma unroll
        for (int i = 0; i < NFEAT; ++i) f[i] = (int)v[i + 2];
    } else {
        #pragma unroll
        for (int i = 0; i < NFEAT; ++i) f[i] = (int)v[i];
    }
    unsigned short r[40];
    r[0] = (unsigned short)f[0];
    r[1] = (unsigned short)(R_AB + f[1]);
    r[2] = (unsigned short)(R_IT + f[2]);
    r[3] = (unsigned short)(R_T1 + f[3] * 4 + f[4] * 2 + f[5]);
    r[4] = (unsigned short)(R_T2 + f[6] * 4 + f[11] * 2 + f[12]);
    r[5] = (unsigned short)(R_T3 + f[7] * 8 + f[8]);
    r[6] = (unsigned short)(R_T4 + f[9] * 2 + f[10]);
    r[7] = (unsigned short)(R_T5 + f[13] * 8 + f[14] * 2 + f[15]);
    r[8] = (unsigned short)(R_T6 + f[16] * 13 + f[17]);
    r[9] = (unsigned short)(R_T7 + f[18] * 13 + f[19]);
    r[10] = (unsigned short)(R_T8 + f[20] * 13 + f[21]);
    r[11] = (unsigned short)(R_T9 + f[22]);
    #pragma unroll
    for (int i = 0; i < 11; ++i) {
        int b = f[23 + i];
        r[12 + 2 * i] = (unsigned short)(R_BITS + i * 512 + (b & 255));
        r[13 + 2 * i] = (unsigned short)(R_BITS + i * 512 + 256 + ((b >> 8) & 255));
    }
    #pragma unroll
    for (int i = 0; i < 4; ++i) r[34 + i] = (unsigned short)(R_ACT + f[34 + i]);
    r[38] = 0; r[39] = 0;
    unsigned int p[20];
    #pragma unroll
    for (int i = 0; i < 20; ++i)
        p[i] = (unsigned int)r[2 * i] | ((unsigned int)r[2 * i + 1] << 16);
    uint4* dst = reinterpret_cast<uint4*>(ridx + (size_t)e * 40);
    dst[0] = make_uint4(p[0], p[1], p[2], p[3]);
    dst[1] = make_uint4(p[4], p[5], p[6], p[7]);
    dst[2] = make_uint4(p[8], p[9], p[10], p[11]);
    dst[3] = make_uint4(p[12], p[13], p[14], p[15]);
    dst[4] = make_uint4(p[16], p[17], p[18], p[19]);
}

// ---------------------------------------------------------------------------
// K2: fused encode + mlp, BARRIER-FREE.  Block = 256 threads (4 waves);
// each wave owns 16 entities end-to-end:
//   phase A: gather-encode 16 entities -> private 16x256 bf16 LDS tile
//            (16B slots rotation-swizzled: phys_slot = (slot + 4*row) & 31)
//   phase B: 8x ds_read_b128 A-frags (reused over nt), 16 nt x 8 MFMA with
//            fragment-ordered wfrag (contiguous 1KB loads), bias+mask, store.
// No __syncthreads: DS ops are in-order within a wave.
// ---------------------------------------------------------------------------
__global__ __launch_bounds__(256) void k_fused_em(
    const unsigned short* __restrict__ ridx, const unsigned short* __restrict__ tbl,
    const unsigned short* __restrict__ wfrag, const float* __restrict__ mlp_b,
    float* __restrict__ out)
{
    __shared__ unsigned short xw[4 * 16 * 256];   // 32,768 B; per-wave 16 rows x 512 B
    __shared__ unsigned int   msk4[4][4];         // 16 mask bytes per wave
    int t    = threadIdx.x;
    int w    = t >> 6;
    int lane = t & 63;
    int half = lane >> 5;
    int cp   = lane & 31;
    int sh   = half << 4;
    int e0   = (blockIdx.x << 6) + (w << 4);      // first entity of this wave
    const char* tb = reinterpret_cast<const char*>(tbl);
    unsigned short* xrow = xw + (w << 12);        // w * 16 * 256

    // ---------------- phase A: encode 16 entities ----------------
    for (int i = 0; i < 16; ++i) {
        int eg = e0 + i;
        const uint4* rp = reinterpret_cast<const uint4*>(ridx + (size_t)eg * 40);
        uint4 r0 = rp[0], r1 = rp[1], r2 = rp[2], r3 = rp[3], r4 = rp[4];
        unsigned int idx32[19] = {r0.x, r0.y, r0.z, r0.w, r1.x, r1.y, r1.z, r1.w,
                                  r2.x, r2.y, r2.z, r2.w, r3.x, r3.y, r3.z, r3.w,
                                  r4.x, r4.y, r4.z};
        float acc[8] = {0.f, 0.f, 0.f, 0.f, 0.f, 0.f, 0.f, 0.f};
        #pragma unroll
        for (int j = 0; j < 19; ++j) {
            unsigned int row = (idx32[j] >> sh) & 0xffffu;
            uint4 v = *reinterpret_cast<const uint4*>(tb + ((size_t)row << 9) + (cp << 4));
            acc[0] += __uint_as_float(v.x << 16);
            acc[1] += __uint_as_float(v.x & 0xffff0000u);
            acc[2] += __uint_as_float(v.y << 16);
            acc[3] += __uint_as_float(v.y & 0xffff0000u);
            acc[4] += __uint_as_float(v.z << 16);
            acc[5] += __uint_as_float(v.z & 0xffff0000u);
            acc[6] += __uint_as_float(v.w << 16);
            acc[7] += __uint_as_float(v.w & 0xffff0000u);
        }
        #pragma unroll
        for (int j = 0; j < 8; ++j) acc[j] += __shfl_xor(acc[j], 32);
        if (lane == 0)
            reinterpret_cast<unsigned char*>(&msk4[w][0])[i] =
                ((r0.x & 0xffffu) < 2u) ? 1 : 0;
        if (half == 0) {
            unsigned int o0 = (unsigned)f2bf(fmaxf(acc[0], 0.f)) | ((unsigned)f2bf(fmaxf(acc[1], 0.f)) << 16);
            unsigned int o1 = (unsigned)f2bf(fmaxf(acc[2], 0.f)) | ((unsigned)f2bf(fmaxf(acc[3], 0.f)) << 16);
            unsigned int o2 = (unsigned)f2bf(fmaxf(acc[4], 0.f)) | ((unsigned)f2bf(fmaxf(acc[5], 0.f)) << 16);
            unsigned int o3 = (unsigned)f2bf(fmaxf(acc[6], 0.f)) | ((unsigned)f2bf(fmaxf(acc[7], 0.f)) << 16);
            int slot = (cp + 4 * i) & 31;
            *reinterpret_cast<uint4*>(&xrow[(i << 8) + (slot << 3)]) = make_uint4(o0, o1, o2, o3);
        }
    }
    __builtin_amdgcn_sched_barrier(0);

    // ---------------- phase B: 16x256 MFMA from own LDS tile ----------------
    int rc = lane & 15;
    int kg = lane >> 4;

    bf16x8 a[8];
    #pragma unroll
    for (int k0g = 0; k0g < 8; ++k0g) {
        int slot = ((k0g << 2) + kg + (rc << 2)) & 31;
        a[k0g] = *reinterpret_cast<const bf16x8*>(&xrow[(rc << 8) + (slot << 3)]);
    }
    unsigned int mw = msk4[w][kg];                 // masks of entities kg*4 .. kg*4+3

    #pragma unroll
    for (int nt = 0; nt < 16; ++nt) {
        f32x4 acc = (f32x4){0.f, 0.f, 0.f, 0.f};
        const bf16x8* bp = reinterpret_cast<const bf16x8*>(
            wfrag + ((size_t)nt << 12) + (lane << 3));
        #pragma unroll
        for (int k0g = 0; k0g < 8; ++k0g)
            acc = __builtin_amdgcn_mfma_f32_16x16x32_bf16(a[k0g], bp[k0g << 6], acc, 0, 0, 0);
        float bias = mlp_b[(nt << 4) + rc];
        #pragma unroll
        for (int j = 0; j < 4; ++j) {
            int row = e0 + (kg << 2) + j;
            bool m = (mw >> (8 * j)) & 1u;
            out[(size_t)row * 256 + (nt << 4) + rc] = m ? 0.f : (acc[j] + bias);
        }
    }
}

// ---------------------------------------------------------------------------
extern "C" void kernel_launch(void* const* d_in, const int* in_sizes, int n_in,
                              void* d_out, int out_size, void* d_ws, size_t ws_size,
                              hipStream_t stream)
{
    const int*   ent     = (const int*)d_in[0];
    const float* sp_tbl  = (const float*)d_in[1];
    const float* ab_tbl  = (const float*)d_in[2];
    const float* it_tbl  = (const float*)d_in[3];
    const float* sp_emb  = (const float*)d_in[4];
    const float* ab_emb  = (const float*)d_in[5];
    const float* it_emb  = (const float*)d_in[6];
    const float* act_emb = (const float*)d_in[7];
    const float* agg_w   = (const float*)d_in[8];
    const float* agg_b   = (const float*)d_in[9];
    const float* mlp_w   = (const float*)d_in[10];
    const float* mlp_b   = (const float*)d_in[11];
    float* out = (float*)d_out;

    char* ws = (char*)d_ws;
    unsigned short* tbl   = (unsigned short*)(ws);               // 8212*512 = 4,204,544 B
    unsigned short* wfrag = (unsigned short*)(ws + 4204544);     //   131,072 B
    unsigned short* ridx  = (unsigned short*)(ws + 4335616);     // 65536*80 = 5,242,880 B

    k_prep    <<<dim3(NB_PREP), dim3(1024), 0, stream>>>(sp_tbl, ab_tbl, it_tbl,
                                                         sp_emb, ab_emb, it_emb,
                                                         act_emb, agg_w, agg_b, mlp_w,
                                                         tbl, wfrag);
    k_idx     <<<dim3(256),     dim3(256),  0, stream>>>(ent, ridx);
    k_fused_em<<<dim3(1024),    dim3(256),  0, stream>>>(ridx, tbl, wfrag, mlp_b, out);
}